// Round 7
// baseline (569.582 us; speedup 1.0000x reference)
//
#include <hip/hip_runtime.h>
#include <math.h>

#define N_ROWS 65536
#define ZDIM   256
#define KCODES 1024
#define IDX_OFF  (N_ROWS * ZDIM)        // 16777216
#define LOSS_OFF (IDX_OFF + N_ROWS)     // 16842752
#define ZQ_BLOCKS 2048

typedef unsigned int u32;

// async global->LDS DMA, 16B per lane, dest = wave-uniform base + lane*16
__device__ __forceinline__ void async16(const float* g, float* l) {
    __builtin_amdgcn_global_load_lds(
        (const __attribute__((address_space(1))) u32*)g,
        (__attribute__((address_space(3))) u32*)l,
        16, 0, 0);
}

// ---------------- numpy-pairwise row sum of squares (256 cols) ----------------
__device__ __forceinline__ float np_pw128_sq(const float* __restrict__ p) {
    float r[8];
#pragma unroll
    for (int j = 0; j < 8; ++j) r[j] = __fmul_rn(p[j], p[j]);
    for (int i = 8; i < 128; i += 8) {
#pragma unroll
        for (int j = 0; j < 8; ++j)
            r[j] = __fadd_rn(r[j], __fmul_rn(p[i + j], p[i + j]));
    }
    float a = __fadd_rn(__fadd_rn(r[0], r[1]), __fadd_rn(r[2], r[3]));
    float b = __fadd_rn(__fadd_rn(r[4], r[5]), __fadd_rn(r[6], r[7]));
    return __fadd_rn(a, b);
}

__global__ void rowsq_kernel(const float* __restrict__ x, float* __restrict__ s, int nrows) {
    int r = blockIdx.x * blockDim.x + threadIdx.x;
    if (r >= nrows) return;
    const float* p = x + (size_t)r * ZDIM;
    s[r] = __fadd_rn(np_pw128_sq(p), np_pw128_sq(p + 128));
}

// ---------------- z transpose: zT[k][row] = z[row][k] ----------------
// grid (4, 1024): 64x64 tiles. zT lives in d_out's z_q region (overwritten
// later by zq_loss, which only reads original z/e/idx).
__global__ __launch_bounds__(256) void transpose_z_kernel(
    const float* __restrict__ z, float* __restrict__ zT) {
    __shared__ float sm[64][65];
    const int t = threadIdx.x;
    const int kb0 = blockIdx.x * 64;
    const int rb0 = blockIdx.y * 64;
    const int c4 = t & 15, rr = t >> 4;
#pragma unroll
    for (int it = 0; it < 4; ++it) {
        int lr = rr + it * 16;
        float4 v = *(const float4*)(z + (size_t)(rb0 + lr) * ZDIM + kb0 + c4 * 4);
        sm[lr][c4 * 4 + 0] = v.x; sm[lr][c4 * 4 + 1] = v.y;
        sm[lr][c4 * 4 + 2] = v.z; sm[lr][c4 * 4 + 3] = v.w;
    }
    __syncthreads();
#pragma unroll
    for (int it = 0; it < 4; ++it) {
        int kl = rr + it * 16;
        float4 w = make_float4(sm[c4 * 4 + 0][kl], sm[c4 * 4 + 1][kl],
                               sm[c4 * 4 + 2][kl], sm[c4 * 4 + 3][kl]);
        *(float4*)(zT + (size_t)(kb0 + kl) * N_ROWS + rb0 + c4 * 4) = w;
    }
}

// ---------------- e transpose with baked perm ----------------
// eT[k][ (c>>8)*256 + perm(c&255) ] = e[c][k], perm(cl)=(cl&3)+4*(cl>>4)+64*((cl>>2)&3)
// grid (4, 16): 64x64 tiles.
__global__ __launch_bounds__(256) void transpose_e_kernel(
    const float* __restrict__ e, float* __restrict__ eT) {
    __shared__ float sm[64][65];
    const int t = threadIdx.x;
    const int kb0 = blockIdx.x * 64;
    const int cb0 = blockIdx.y * 64;
    const int c4 = t & 15, rr = t >> 4;
#pragma unroll
    for (int it = 0; it < 4; ++it) {
        int lc = rr + it * 16;
        float4 v = *(const float4*)(e + (size_t)(cb0 + lc) * ZDIM + kb0 + c4 * 4);
        sm[lc][c4 * 4 + 0] = v.x; sm[lc][c4 * 4 + 1] = v.y;
        sm[lc][c4 * 4 + 2] = v.z; sm[lc][c4 * 4 + 3] = v.w;
    }
    __syncthreads();
    const int cg = cb0 + c4 * 4;            // global code, ==0 mod 4
    const int cl = cg & 255;
    const int base = ((cg >> 8) << 8) + 4 * (cl >> 4) + 64 * ((cl >> 2) & 3);
#pragma unroll
    for (int it = 0; it < 4; ++it) {
        int kl = rr + it * 16;
        float4 w = make_float4(sm[c4 * 4 + 0][kl], sm[c4 * 4 + 1][kl],
                               sm[c4 * 4 + 2][kl], sm[c4 * 4 + 3][kl]);
        *(float4*)(eT + (size_t)(kb0 + kl) * KCODES + base) = w;
    }
}

// ---------------- distance + argmin kernel (v7: DMA e-staging, direct-z) ----
// Grid 512, block 256 (tr=row-group 0..15, tc=code-group 0..15), tile
// 128 rows x 1024 codes, thread tile 8x16. Phases: 4 ct x 8 kc.
// e: global_load_lds DMA into et[32][256] (perm pre-baked -> ds_read banks
// 2-way-free, code = ct*256 + 16*tc + 4*jq + w). z: fragments read directly
// from pre-transposed zT (32B contiguous/thread/k, L2-resident).
// k-ascending fmaf chain per (row,code) -> bit-exact vs np/OpenBLAS.
__global__ __launch_bounds__(256) void argmin_kernel(
    const float* __restrict__ zT, const float* __restrict__ eT,
    const float* __restrict__ sz, const float* __restrict__ se,
    int* __restrict__ out_idx, float* __restrict__ out_idx_f) {
    __shared__ float et[32 * 256];      // 32 KB
    __shared__ float sse[KCODES];       // 4 KB
    __shared__ float2 red[128 * 16];    // 16 KB
    const int tid = threadIdx.x;
    const int tc = tid & 15;
    const int tr = tid >> 4;
    const int wave = tid >> 6;
    const int lane = tid & 63;
    const int br0 = blockIdx.x * 128;

    *(float4*)(sse + tid * 4) = *(const float4*)(se + tid * 4);

    float szr[8];
#pragma unroll
    for (int r = 0; r < 8; ++r) szr[r] = sz[br0 + tr * 8 + r];

    float bestd[8];
    int   besti[8];
#pragma unroll
    for (int r = 0; r < 8; ++r) { bestd[r] = __builtin_inff(); besti[r] = 0; }

    const float* zrow0 = zT + br0 + tr * 8;   // + k*N_ROWS per k

    float acc[8][16];

    for (int ct = 0; ct < 4; ++ct) {
#pragma unroll
        for (int r = 0; r < 8; ++r)
#pragma unroll
            for (int c = 0; c < 16; ++c) acc[r][c] = 0.0f;

        for (int kc = 0; kc < 8; ++kc) {
            const int kb = kc * 32;
            // DMA e tile: 32 rows of 1KB; wave w handles k = w*8..w*8+7
#pragma unroll
            for (int i = 0; i < 8; ++i) {
                const int ke = wave * 8 + i;
                async16(eT + (size_t)(kb + ke) * KCODES + ct * 256 + lane * 4,
                        et + ke * 256);
            }
            __syncthreads();   // drains vmcnt (DMA) before reads
#pragma unroll 1
            for (int g4 = 0; g4 < 8; ++g4) {
                float4 zA[4], zB[4];
#pragma unroll
                for (int kk = 0; kk < 4; ++kk) {
                    const float* zp = zrow0 + (size_t)(kb + g4 * 4 + kk) * N_ROWS;
                    zA[kk] = *(const float4*)zp;
                    zB[kk] = *(const float4*)(zp + 4);
                }
#pragma unroll
                for (int kk = 0; kk < 4; ++kk) {
                    const int k = g4 * 4 + kk;
                    const float* erow = et + k * 256 + (tc << 2);
                    float4 e0 = *(const float4*)erow;
                    float4 e1 = *(const float4*)(erow + 64);
                    float4 e2 = *(const float4*)(erow + 128);
                    float4 e3 = *(const float4*)(erow + 192);
                    float zf[8]  = {zA[kk].x, zA[kk].y, zA[kk].z, zA[kk].w,
                                    zB[kk].x, zB[kk].y, zB[kk].z, zB[kk].w};
                    float ef[16] = {e0.x, e0.y, e0.z, e0.w, e1.x, e1.y, e1.z, e1.w,
                                    e2.x, e2.y, e2.z, e2.w, e3.x, e3.y, e3.z, e3.w};
#pragma unroll
                    for (int r = 0; r < 8; ++r)
#pragma unroll
                        for (int c = 0; c < 16; ++c)
                            acc[r][c] = fmaf(zf[r], ef[c], acc[r][c]);
                }
            }
            __syncthreads();   // protect et from next phase's DMA
        }
        // epilogue: codes ascending (ct asc, j asc); strict < keeps first
#pragma unroll
        for (int j = 0; j < 16; ++j) {
            int code = ct * 256 + tc * 16 + j;
            float sec = sse[code];
#pragma unroll
            for (int r = 0; r < 8; ++r) {
                float t = __fadd_rn(szr[r], sec);
                float d = __fsub_rn(t, 2.0f * acc[r][j]);
                if (d < bestd[r]) { bestd[r] = d; besti[r] = code; }
            }
        }
    }

    // cross-thread reduction: lexicographic (d, idx) min == first-occurrence
#pragma unroll
    for (int r = 0; r < 8; ++r)
        red[(tr * 8 + r) * 16 + tc] = make_float2(bestd[r], (float)besti[r]);
    __syncthreads();
    if (tid < 128) {
        float bd = __builtin_inff();
        float bi = 0.0f;
        for (int t = 0; t < 16; ++t) {
            float2 v = red[tid * 16 + t];
            if (v.x < bd || (v.x == bd && v.y < bi)) { bd = v.x; bi = v.y; }
        }
        out_idx[br0 + tid]   = (int)bi;
        out_idx_f[br0 + tid] = bi;
    }
}

// ---------------- z_q_st + loss partial (no atomics) ----------------
__global__ __launch_bounds__(256) void zq_loss_kernel(
    const float* __restrict__ z, const float* __restrict__ e,
    const int* __restrict__ idx, float* __restrict__ out,
    double* __restrict__ partial) {
    const int tid = threadIdx.x;
    const int rl  = tid >> 6;
    const int ln  = tid & 63;
    const int row0 = blockIdx.x * 32;

    float acc = 0.0f;
#pragma unroll
    for (int it = 0; it < 8; ++it) {
        int row = row0 + it * 4 + rl;
        int code = idx[row];
        const float4 vz = *(const float4*)(z + (size_t)row  * ZDIM + ln * 4);
        const float4 vq = *(const float4*)(e + (size_t)code * ZDIM + ln * 4);
        float4 o;
        float dx = __fsub_rn(vq.x, vz.x);
        float dy = __fsub_rn(vq.y, vz.y);
        float dz_ = __fsub_rn(vq.z, vz.z);
        float dw = __fsub_rn(vq.w, vz.w);
        o.x = __fadd_rn(vz.x, dx);
        o.y = __fadd_rn(vz.y, dy);
        o.z = __fadd_rn(vz.z, dz_);
        o.w = __fadd_rn(vz.w, dw);
        *(float4*)(out + (size_t)row * ZDIM + ln * 4) = o;
        acc = __fadd_rn(acc, __fmul_rn(dx, dx));
        acc = __fadd_rn(acc, __fmul_rn(dy, dy));
        acc = __fadd_rn(acc, __fmul_rn(dz_, dz_));
        acc = __fadd_rn(acc, __fmul_rn(dw, dw));
    }

    __shared__ double red[256];
    red[tid] = (double)acc;
    __syncthreads();
#pragma unroll
    for (int s = 128; s > 0; s >>= 1) {
        if (tid < s) red[tid] += red[tid + s];
        __syncthreads();
    }
    if (tid == 0) partial[blockIdx.x] = red[0];
}

__global__ __launch_bounds__(256) void loss_final_kernel(
    const double* __restrict__ partial, float* __restrict__ out_loss) {
    const int tid = threadIdx.x;
    double s = 0.0;
    for (int i = tid; i < ZQ_BLOCKS; i += 256) s += partial[i];
    __shared__ double red[256];
    red[tid] = s;
    __syncthreads();
#pragma unroll
    for (int st = 128; st > 0; st >>= 1) {
        if (tid < st) red[tid] += red[tid + st];
        __syncthreads();
    }
    if (tid == 0) {
        double M = red[0] / 16777216.0;
        float m32 = (float)M;
        out_loss[0] = __fadd_rn(m32, __fmul_rn(0.25f, m32));
    }
}

extern "C" void kernel_launch(void* const* d_in, const int* in_sizes, int n_in,
                              void* d_out, int out_size, void* d_ws, size_t ws_size,
                              hipStream_t stream) {
    const float* z = (const float*)d_in[0];
    const float* e = (const float*)d_in[1];
    float* out = (float*)d_out;
    char* ws = (char*)d_ws;

    size_t off = 0;
    double* partial = (double*)(ws + off); off += ZQ_BLOCKS * sizeof(double);   // 16 KB
    float*  sz      = (float*) (ws + off); off += (size_t)N_ROWS * 4;           // 256 KB
    float*  se      = (float*) (ws + off); off += (size_t)KCODES * 4;           // 4 KB
    int*    idx     = (int*)   (ws + off); off += (size_t)N_ROWS * 4;           // 256 KB
    float*  eT      = (float*) (ws + off); off += (size_t)ZDIM * KCODES * 4;    // 1 MB

    float* zT = out;   // reuse d_out z_q region; zq_loss overwrites it later

    transpose_z_kernel<<<dim3(4, 1024), 256, 0, stream>>>(z, zT);
    transpose_e_kernel<<<dim3(4, 16),   256, 0, stream>>>(e, eT);
    rowsq_kernel<<<N_ROWS / 256, 256, 0, stream>>>(z, sz, N_ROWS);
    rowsq_kernel<<<KCODES / 256, 256, 0, stream>>>(e, se, KCODES);
    argmin_kernel<<<N_ROWS / 128, 256, 0, stream>>>(zT, eT, sz, se, idx, out + IDX_OFF);
    zq_loss_kernel<<<ZQ_BLOCKS, 256, 0, stream>>>(z, e, idx, out, partial);
    loss_final_kernel<<<1, 256, 0, stream>>>(partial, out + LOSS_OFF);
}

// Round 8
// 543.152 us; speedup vs baseline: 1.0487x; 1.0487x over previous
//
#include <hip/hip_runtime.h>
#include <math.h>

#define N_ROWS 65536
#define ZDIM   256
#define KCODES 1024
#define IDX_OFF  (N_ROWS * ZDIM)        // 16777216
#define LOSS_OFF (IDX_OFF + N_ROWS)     // 16842752
#define ZQ_BLOCKS 2048
#define NPART 2

typedef unsigned int u32;

// async global->LDS DMA, 16B per lane, dest = wave-uniform base + lane*16
__device__ __forceinline__ void async16(const float* g, float* l) {
    __builtin_amdgcn_global_load_lds(
        (const __attribute__((address_space(1))) u32*)g,
        (__attribute__((address_space(3))) u32*)l,
        16, 0, 0);
}

// ---------------- numpy-pairwise row sum of squares (256 cols) ----------------
__device__ __forceinline__ float np_pw128_sq(const float* __restrict__ p) {
    float r[8];
#pragma unroll
    for (int j = 0; j < 8; ++j) r[j] = __fmul_rn(p[j], p[j]);
    for (int i = 8; i < 128; i += 8) {
#pragma unroll
        for (int j = 0; j < 8; ++j)
            r[j] = __fadd_rn(r[j], __fmul_rn(p[i + j], p[i + j]));
    }
    float a = __fadd_rn(__fadd_rn(r[0], r[1]), __fadd_rn(r[2], r[3]));
    float b = __fadd_rn(__fadd_rn(r[4], r[5]), __fadd_rn(r[6], r[7]));
    return __fadd_rn(a, b);
}

__global__ void rowsq_kernel(const float* __restrict__ x, float* __restrict__ s, int nrows) {
    int r = blockIdx.x * blockDim.x + threadIdx.x;
    if (r >= nrows) return;
    const float* p = x + (size_t)r * ZDIM;
    s[r] = __fadd_rn(np_pw128_sq(p), np_pw128_sq(p + 128));
}

// ---------------- z transpose: zT[k][row] = z[row][k] ----------------
__global__ __launch_bounds__(256) void transpose_z_kernel(
    const float* __restrict__ z, float* __restrict__ zT) {
    __shared__ float sm[64][65];
    const int t = threadIdx.x;
    const int kb0 = blockIdx.x * 64;
    const int rb0 = blockIdx.y * 64;
    const int c4 = t & 15, rr = t >> 4;
#pragma unroll
    for (int it = 0; it < 4; ++it) {
        int lr = rr + it * 16;
        float4 v = *(const float4*)(z + (size_t)(rb0 + lr) * ZDIM + kb0 + c4 * 4);
        sm[lr][c4 * 4 + 0] = v.x; sm[lr][c4 * 4 + 1] = v.y;
        sm[lr][c4 * 4 + 2] = v.z; sm[lr][c4 * 4 + 3] = v.w;
    }
    __syncthreads();
#pragma unroll
    for (int it = 0; it < 4; ++it) {
        int kl = rr + it * 16;
        float4 w = make_float4(sm[c4 * 4 + 0][kl], sm[c4 * 4 + 1][kl],
                               sm[c4 * 4 + 2][kl], sm[c4 * 4 + 3][kl]);
        *(float4*)(zT + (size_t)(kb0 + kl) * N_ROWS + rb0 + c4 * 4) = w;
    }
}

// ---------------- e transpose: eT[k][c] = e[c][k] (plain) ----------------
__global__ __launch_bounds__(256) void transpose_e_kernel(
    const float* __restrict__ e, float* __restrict__ eT) {
    __shared__ float sm[64][65];
    const int t = threadIdx.x;
    const int kb0 = blockIdx.x * 64;
    const int cb0 = blockIdx.y * 64;
    const int c4 = t & 15, rr = t >> 4;
#pragma unroll
    for (int it = 0; it < 4; ++it) {
        int lc = rr + it * 16;
        float4 v = *(const float4*)(e + (size_t)(cb0 + lc) * ZDIM + kb0 + c4 * 4);
        sm[lc][c4 * 4 + 0] = v.x; sm[lc][c4 * 4 + 1] = v.y;
        sm[lc][c4 * 4 + 2] = v.z; sm[lc][c4 * 4 + 3] = v.w;
    }
    __syncthreads();
#pragma unroll
    for (int it = 0; it < 4; ++it) {
        int kl = rr + it * 16;
        float4 w = make_float4(sm[c4 * 4 + 0][kl], sm[c4 * 4 + 1][kl],
                               sm[c4 * 4 + 2][kl], sm[c4 * 4 + 3][kl]);
        *(float4*)(eT + (size_t)(kb0 + kl) * KCODES + cb0 + c4 * 4) = w;
    }
}

// ---------------- distance + argmin kernel (v8) ----------------
// Grid 1024 = 512 row-panels x 2 code-parts. Block 256 thr, tile 128 rows x
// 512 codes, thread tile 8x16. 32 phases (2 ct x 16 kc of 16 dims).
// ALL staging via global_load_lds DMA from zT/eT, double-buffered, DMA(p+1)
// issued at top of phase p, ONE __syncthreads per phase (its implicit
// vmcnt(0) drain lands ~4k cycles after issue -> free).
// Reads: z frags broadcast-16 (banks 0/8/16/24, conflict-free), e frags
// 2-way (free). No swizzle needed (no per-element LDS writes).
// k-ascending fmaf chain per (row,code); thread code-visit order ascending;
// lexicographic (d,idx) merges -> bit-exact np/OpenBLAS argmin semantics.
__global__ __launch_bounds__(256) void argmin_part_kernel(
    const float* __restrict__ zT, const float* __restrict__ eT,
    const float* __restrict__ sz, const float* __restrict__ se,
    float* __restrict__ cand_d, int* __restrict__ cand_i) {
    __shared__ float zt[2][16 * 128];   // 16 KB
    __shared__ float et[2][16 * 256];   // 32 KB
    __shared__ float sse[512];          //  2 KB
    const int tid  = threadIdx.x;
    const int tc   = tid & 15;
    const int tr   = tid >> 4;
    const int wave = tid >> 6;
    const int lane = tid & 63;
    const int rp  = blockIdx.x >> 1;
    const int pp  = blockIdx.x & 1;
    const int br0 = rp * 128;
    const int ce0 = pp * 512;

    sse[tid]       = se[ce0 + tid];
    sse[tid + 256] = se[ce0 + tid + 256];

    float szr[8];
#pragma unroll
    for (int r = 0; r < 8; ++r) szr[r] = sz[br0 + tr * 8 + r];

    float bestd[8];
    int   besti[8];
#pragma unroll
    for (int r = 0; r < 8; ++r) { bestd[r] = __builtin_inff(); besti[r] = 0; }

    // DMA one phase's tiles (16 k-dims) into buffer buf
    auto dma_phase = [&](int p, int buf) {
        const int ct = p >> 4;
        const int kb = (p & 15) * 16;
        // z: 16 rows x 128 floats; 2 instrs/wave, each covers 2 k-rows
#pragma unroll
        for (int j = 0; j < 2; ++j) {
            const int kr = wave * 4 + 2 * j;
            async16(zT + (size_t)(kb + kr + (lane >> 5)) * N_ROWS + br0 + (lane & 31) * 4,
                    &zt[buf][kr * 128]);
        }
        // e: 16 rows x 256 floats; 4 instrs/wave, 1 k-row each
#pragma unroll
        for (int i = 0; i < 4; ++i) {
            const int kr = wave * 4 + i;
            async16(eT + (size_t)(kb + kr) * KCODES + ce0 + ct * 256 + lane * 4,
                    &et[buf][kr * 256]);
        }
    };

    float acc[8][16];

    dma_phase(0, 0);
    __syncthreads();

#pragma unroll 1
    for (int p = 0; p < 32; ++p) {
        const int buf = p & 1;
        const int ct = p >> 4;
        const int kc = p & 15;
        if (kc == 0) {
#pragma unroll
            for (int r = 0; r < 8; ++r)
#pragma unroll
                for (int c = 0; c < 16; ++c) acc[r][c] = 0.0f;
        }
        if (p < 31) dma_phase(p + 1, buf ^ 1);

        const float* ztb = zt[buf];
        const float* etb = et[buf];
#pragma unroll 1
        for (int kq = 0; kq < 4; ++kq) {
#pragma unroll
            for (int kk = 0; kk < 4; ++kk) {
                const int k = kq * 4 + kk;
                const float* zp = ztb + k * 128 + tr * 8;
                const float4 za = *(const float4*)zp;
                const float4 zb = *(const float4*)(zp + 4);
                const float* ep = etb + k * 256 + (tc << 2);
                const float4 e0 = *(const float4*)ep;
                const float4 e1 = *(const float4*)(ep + 64);
                const float4 e2 = *(const float4*)(ep + 128);
                const float4 e3 = *(const float4*)(ep + 192);
                float zf[8]  = {za.x, za.y, za.z, za.w, zb.x, zb.y, zb.z, zb.w};
                float ef[16] = {e0.x, e0.y, e0.z, e0.w, e1.x, e1.y, e1.z, e1.w,
                                e2.x, e2.y, e2.z, e2.w, e3.x, e3.y, e3.z, e3.w};
#pragma unroll
                for (int r = 0; r < 8; ++r)
#pragma unroll
                    for (int c = 0; c < 16; ++c)
                        acc[r][c] = fmaf(zf[r], ef[c], acc[r][c]);
            }
        }

        if (kc == 15) {
            // codes ascending in jj for fixed thread; strict < keeps first
#pragma unroll
            for (int jj = 0; jj < 16; ++jj) {
                const int lc = ct * 256 + (jj >> 2) * 64 + (tc << 2) + (jj & 3);
                const float sec = sse[lc];
#pragma unroll
                for (int r = 0; r < 8; ++r) {
                    float t = __fadd_rn(szr[r], sec);
                    float d = __fsub_rn(t, 2.0f * acc[r][jj]);
                    if (d < bestd[r]) { bestd[r] = d; besti[r] = ce0 + lc; }
                }
            }
        }
        __syncthreads();
    }

    // cross-thread reduction: lexicographic (d, idx) min == first-occurrence
    float2* red = (float2*)&zt[0][0];   // 16 KB, z buffers dead now
#pragma unroll
    for (int r = 0; r < 8; ++r)
        red[(tr * 8 + r) * 16 + tc] = make_float2(bestd[r], (float)besti[r]);
    __syncthreads();
    if (tid < 128) {
        float bd = __builtin_inff();
        float bi = 0.0f;
        for (int t = 0; t < 16; ++t) {
            float2 v = red[tid * 16 + t];
            if (v.x < bd || (v.x == bd && v.y < bi)) { bd = v.x; bi = v.y; }
        }
        cand_d[(size_t)pp * N_ROWS + br0 + tid] = bd;
        cand_i[(size_t)pp * N_ROWS + br0 + tid] = (int)bi;
    }
}

// ---------------- merge 2 code-part candidates ----------------
__global__ __launch_bounds__(256) void argmin_merge_kernel(
    const float* __restrict__ cand_d, const int* __restrict__ cand_i,
    int* __restrict__ out_idx, float* __restrict__ out_idx_f) {
    int row = blockIdx.x * 256 + threadIdx.x;
    float bd = __builtin_inff();
    int   bi = 0;
#pragma unroll
    for (int pp = 0; pp < NPART; ++pp) {
        float d = cand_d[(size_t)pp * N_ROWS + row];
        int   i = cand_i[(size_t)pp * N_ROWS + row];
        if (d < bd) { bd = d; bi = i; }
    }
    out_idx[row]   = bi;
    out_idx_f[row] = (float)bi;
}

// ---------------- z_q_st + loss partial (no atomics) ----------------
__global__ __launch_bounds__(256) void zq_loss_kernel(
    const float* __restrict__ z, const float* __restrict__ e,
    const int* __restrict__ idx, float* __restrict__ out,
    double* __restrict__ partial) {
    const int tid = threadIdx.x;
    const int rl  = tid >> 6;
    const int ln  = tid & 63;
    const int row0 = blockIdx.x * 32;

    float acc = 0.0f;
#pragma unroll
    for (int it = 0; it < 8; ++it) {
        int row = row0 + it * 4 + rl;
        int code = idx[row];
        const float4 vz = *(const float4*)(z + (size_t)row  * ZDIM + ln * 4);
        const float4 vq = *(const float4*)(e + (size_t)code * ZDIM + ln * 4);
        float4 o;
        float dx = __fsub_rn(vq.x, vz.x);
        float dy = __fsub_rn(vq.y, vz.y);
        float dz_ = __fsub_rn(vq.z, vz.z);
        float dw = __fsub_rn(vq.w, vz.w);
        o.x = __fadd_rn(vz.x, dx);
        o.y = __fadd_rn(vz.y, dy);
        o.z = __fadd_rn(vz.z, dz_);
        o.w = __fadd_rn(vz.w, dw);
        *(float4*)(out + (size_t)row * ZDIM + ln * 4) = o;
        acc = __fadd_rn(acc, __fmul_rn(dx, dx));
        acc = __fadd_rn(acc, __fmul_rn(dy, dy));
        acc = __fadd_rn(acc, __fmul_rn(dz_, dz_));
        acc = __fadd_rn(acc, __fmul_rn(dw, dw));
    }

    __shared__ double red[256];
    red[tid] = (double)acc;
    __syncthreads();
#pragma unroll
    for (int s = 128; s > 0; s >>= 1) {
        if (tid < s) red[tid] += red[tid + s];
        __syncthreads();
    }
    if (tid == 0) partial[blockIdx.x] = red[0];
}

__global__ __launch_bounds__(256) void loss_final_kernel(
    const double* __restrict__ partial, float* __restrict__ out_loss) {
    const int tid = threadIdx.x;
    double s = 0.0;
    for (int i = tid; i < ZQ_BLOCKS; i += 256) s += partial[i];
    __shared__ double red[256];
    red[tid] = s;
    __syncthreads();
#pragma unroll
    for (int st = 128; st > 0; st >>= 1) {
        if (tid < st) red[tid] += red[tid + st];
        __syncthreads();
    }
    if (tid == 0) {
        double M = red[0] / 16777216.0;
        float m32 = (float)M;
        out_loss[0] = __fadd_rn(m32, __fmul_rn(0.25f, m32));
    }
}

extern "C" void kernel_launch(void* const* d_in, const int* in_sizes, int n_in,
                              void* d_out, int out_size, void* d_ws, size_t ws_size,
                              hipStream_t stream) {
    const float* z = (const float*)d_in[0];
    const float* e = (const float*)d_in[1];
    float* out = (float*)d_out;
    char* ws = (char*)d_ws;

    size_t off = 0;
    double* partial = (double*)(ws + off); off += ZQ_BLOCKS * sizeof(double);   // 16 KB
    float*  sz      = (float*) (ws + off); off += (size_t)N_ROWS * 4;           // 256 KB
    float*  se      = (float*) (ws + off); off += (size_t)KCODES * 4;           // 4 KB
    int*    idx     = (int*)   (ws + off); off += (size_t)N_ROWS * 4;           // 256 KB
    float*  cand_d  = (float*) (ws + off); off += (size_t)NPART * N_ROWS * 4;   // 512 KB
    int*    cand_i  = (int*)   (ws + off); off += (size_t)NPART * N_ROWS * 4;   // 512 KB
    float*  eT      = (float*) (ws + off); off += (size_t)ZDIM * KCODES * 4;    // 1 MB

    float* zT = out;   // reuse d_out z_q region; zq_loss overwrites it later

    transpose_z_kernel<<<dim3(4, 1024), 256, 0, stream>>>(z, zT);
    transpose_e_kernel<<<dim3(4, 16),   256, 0, stream>>>(e, eT);
    rowsq_kernel<<<N_ROWS / 256, 256, 0, stream>>>(z, sz, N_ROWS);
    rowsq_kernel<<<KCODES / 256, 256, 0, stream>>>(e, se, KCODES);
    argmin_part_kernel<<<(N_ROWS / 128) * NPART, 256, 0, stream>>>(zT, eT, sz, se, cand_d, cand_i);
    argmin_merge_kernel<<<N_ROWS / 256, 256, 0, stream>>>(cand_d, cand_i, idx, out + IDX_OFF);
    zq_loss_kernel<<<ZQ_BLOCKS, 256, 0, stream>>>(z, e, idx, out, partial);
    loss_final_kernel<<<1, 256, 0, stream>>>(partial, out + LOSS_OFF);
}

// Round 9
// 426.998 us; speedup vs baseline: 1.3339x; 1.2720x over previous
//
#include <hip/hip_runtime.h>
#include <hip/hip_bf16.h>
#include <math.h>

#define N_ROWS 65536
#define ZDIM   256
#define KCODES 1024
#define IDX_OFF  (N_ROWS * ZDIM)        // 16777216
#define LOSS_OFF (IDX_OFF + N_ROWS)     // 16842752
#define ZQ_BLOCKS 2048
#define SLOTS 4
#define EPS2 2.5e-4f

typedef unsigned int u32;
typedef unsigned short u16;
typedef __attribute__((ext_vector_type(8))) short bfrag;   // 8 bf16 (4 VGPR)
typedef __attribute__((ext_vector_type(4))) float ffrag;   // 4 fp32 acc

__device__ __forceinline__ u16 f2bf(float x) {
    __hip_bfloat16 h = __float2bfloat16(x);      // RN
    union { __hip_bfloat16 h; u16 u; } c; c.h = h; return c.u;
}
__device__ __forceinline__ float bf2f(u16 u) {
    union { u16 u; __hip_bfloat16 h; } c; c.u = u;
    return __bfloat162float(c.h);
}

// ---------------- numpy-pairwise row sum of squares (256 cols) ----------------
__device__ __forceinline__ float np_pw128_sq(const float* __restrict__ p) {
    float r[8];
#pragma unroll
    for (int j = 0; j < 8; ++j) r[j] = __fmul_rn(p[j], p[j]);
    for (int i = 8; i < 128; i += 8) {
#pragma unroll
        for (int j = 0; j < 8; ++j)
            r[j] = __fadd_rn(r[j], __fmul_rn(p[i + j], p[i + j]));
    }
    float a = __fadd_rn(__fadd_rn(r[0], r[1]), __fadd_rn(r[2], r[3]));
    float b = __fadd_rn(__fadd_rn(r[4], r[5]), __fadd_rn(r[6], r[7]));
    return __fadd_rn(a, b);
}

__global__ void rowsq_kernel(const float* __restrict__ x, float* __restrict__ s, int nrows) {
    int r = blockIdx.x * blockDim.x + threadIdx.x;
    if (r >= nrows) return;
    const float* p = x + (size_t)r * ZDIM;
    s[r] = __fadd_rn(np_pw128_sq(p), np_pw128_sq(p + 128));
}

// ---------------- z split: word = (bits(zl)<<16) | bits(zh) --------------------
// zh = bf16_rn(z), zl = bf16_rn(z - zh). Stored in d_out z_q region (64 MB),
// consumed by mfma kernel, later overwritten by zq_loss.
__global__ __launch_bounds__(256) void split_z_kernel(
    const float* __restrict__ z, u32* __restrict__ zs) {
    int t = blockIdx.x * 256 + threadIdx.x;       // 524288 threads
#pragma unroll
    for (int it = 0; it < 8; ++it) {
        int i = (it * 524288 + t) * 4;
        float4 v = *(const float4*)(z + i);
        uint4 w;
        float x;
        u16 h, l;
        x = v.x; h = f2bf(x); l = f2bf(__fsub_rn(x, bf2f(h))); w.x = ((u32)l << 16) | h;
        x = v.y; h = f2bf(x); l = f2bf(__fsub_rn(x, bf2f(h))); w.y = ((u32)l << 16) | h;
        x = v.z; h = f2bf(x); l = f2bf(__fsub_rn(x, bf2f(h))); w.z = ((u32)l << 16) | h;
        x = v.w; h = f2bf(x); l = f2bf(__fsub_rn(x, bf2f(h))); w.w = ((u32)l << 16) | h;
        *(uint4*)(zs + i) = w;
    }
}

// ---------------- e split: separate bf16 arrays (k-contiguous) ----------------
__global__ __launch_bounds__(256) void split_e_kernel(
    const float* __restrict__ e, u16* __restrict__ eh, u16* __restrict__ el) {
    int t = blockIdx.x * 256 + threadIdx.x;       // 65536 threads x 4 elems
    int i = t * 4;
    float4 v = *(const float4*)(e + i);
    ushort4 hh, ll;
    u16 h;
    h = f2bf(v.x); hh.x = h; ll.x = f2bf(__fsub_rn(v.x, bf2f(h)));
    h = f2bf(v.y); hh.y = h; ll.y = f2bf(__fsub_rn(v.y, bf2f(h)));
    h = f2bf(v.z); hh.z = h; ll.z = f2bf(__fsub_rn(v.z, bf2f(h)));
    h = f2bf(v.w); hh.w = h; ll.w = f2bf(__fsub_rn(v.w, bf2f(h)));
    *(ushort4*)(eh + i) = hh;
    *(ushort4*)(el + i) = ll;
}

// ---------------- MFMA approximate-distance + candidate emission ----------------
// Grid 512 x 256 thr (4 waves). Block: 128 rows; wave w: rows wr0=br0+w*32,
// all 1024 codes via 4 code-quarters (cq). acc[rt2][ct16] f32x4 per wave.
// m~ = zh.eh + zh.el + zl.eh (3-pass bf16 MFMA, fp32 acc). |d~ - d_exact| <=
// ~4.5e-5 worst-case (zl.el + split residues + fp32 accum); EPS2=2.5e-4 = 5.5x.
// Per cq: per-row min (4x shfl_xor over the 16 lanes holding one row's cols),
// write cqmin, emit codes with d~ <= rmin+EPS2 (atomic slots; overflow -> scan
// fallback in rescore). Fragment layouts (gfx950 16x16x32 bf16):
//   A: row=lane&15, k=(lane>>4)*8+j (8 contiguous k)
//   B: col=lane&15, k=(lane>>4)*8+j
//   D: col=lane&15, row=(lane>>4)*4+reg  [m89-verified]
// e staged in LDS stride-40-shorts: read banks (20a+4b)%32 = uniform 2-way = free.
__global__ __launch_bounds__(256) void mfma_argmin_kernel(
    const u32* __restrict__ zs, const u16* __restrict__ ehg,
    const u16* __restrict__ elg, const float* __restrict__ sz,
    const float* __restrict__ se, float* __restrict__ cqmin,
    int* __restrict__ cnt, int* __restrict__ cand) {
    __shared__ short ehL[256 * 40];    // 20 KB
    __shared__ short elL[256 * 40];    // 20 KB
    __shared__ float sse[KCODES];      //  4 KB
    const int tid = threadIdx.x;
    const int w = tid >> 6, lane = tid & 63;
    const int lr = lane & 15, lk = lane >> 4;
    const int br0 = blockIdx.x * 128;
    const int wr0 = br0 + w * 32;

    *(float4*)(sse + tid * 4) = *(const float4*)(se + tid * 4);

    float szv[2][4];
#pragma unroll
    for (int rt = 0; rt < 2; ++rt)
#pragma unroll
        for (int j = 0; j < 4; ++j)
            szv[rt][j] = sz[wr0 + rt * 16 + lk * 4 + j];

    ffrag acc[2][16];

#pragma unroll 1
    for (int cq = 0; cq < 4; ++cq) {
#pragma unroll
        for (int rt = 0; rt < 2; ++rt)
#pragma unroll
            for (int ct = 0; ct < 16; ++ct)
                acc[rt][ct] = (ffrag)(0.0f);

#pragma unroll 1
        for (int kc = 0; kc < 8; ++kc) {
            // stage eh/el chunk: thread t -> code t, 64B each (4 x uint4)
            {
                const u16* gp = ehg + ((size_t)(cq * 256 + tid)) * 256 + kc * 32;
                const u16* gq = elg + ((size_t)(cq * 256 + tid)) * 256 + kc * 32;
                short* lp = ehL + tid * 40;
                short* lq = elL + tid * 40;
#pragma unroll
                for (int p = 0; p < 4; ++p) {
                    *(uint4*)(lp + p * 8) = *(const uint4*)(gp + p * 8);
                    *(uint4*)(lq + p * 8) = *(const uint4*)(gq + p * 8);
                }
            }
            __syncthreads();
            // A frags from packed zsplit: 2 x uint4 -> zh (lo16) + zl (hi16)
            bfrag ah[2], al[2];
#pragma unroll
            for (int rt = 0; rt < 2; ++rt) {
                const u32* zp = zs + ((size_t)(wr0 + rt * 16 + lr)) * 256 + kc * 32 + lk * 8;
                uint4 w0 = *(const uint4*)zp;
                uint4 w1 = *(const uint4*)(zp + 4);
                u32 ws_[8] = {w0.x, w0.y, w0.z, w0.w, w1.x, w1.y, w1.z, w1.w};
#pragma unroll
                for (int i2 = 0; i2 < 8; ++i2) {
                    ah[rt][i2] = (short)(ws_[i2] & 0xffffu);
                    al[rt][i2] = (short)(ws_[i2] >> 16);
                }
            }
#pragma unroll
            for (int ct = 0; ct < 16; ++ct) {
                bfrag bh = *(const bfrag*)(ehL + ct * 640 + lr * 40 + lk * 8);
                bfrag bl = *(const bfrag*)(elL + ct * 640 + lr * 40 + lk * 8);
                acc[0][ct] = __builtin_amdgcn_mfma_f32_16x16x32_bf16(ah[0], bh, acc[0][ct], 0, 0, 0);
                acc[1][ct] = __builtin_amdgcn_mfma_f32_16x16x32_bf16(ah[1], bh, acc[1][ct], 0, 0, 0);
                acc[0][ct] = __builtin_amdgcn_mfma_f32_16x16x32_bf16(ah[0], bl, acc[0][ct], 0, 0, 0);
                acc[1][ct] = __builtin_amdgcn_mfma_f32_16x16x32_bf16(ah[1], bl, acc[1][ct], 0, 0, 0);
                acc[0][ct] = __builtin_amdgcn_mfma_f32_16x16x32_bf16(al[0], bh, acc[0][ct], 0, 0, 0);
                acc[1][ct] = __builtin_amdgcn_mfma_f32_16x16x32_bf16(al[1], bh, acc[1][ct], 0, 0, 0);
            }
            __syncthreads();
        }

        // ---- epilogue for cq: d~ = fl(fl(sz+se) - 2*m~) ----
        float rmin[2][4];
#pragma unroll
        for (int rt = 0; rt < 2; ++rt)
#pragma unroll
            for (int j = 0; j < 4; ++j) rmin[rt][j] = __builtin_inff();
#pragma unroll
        for (int rt = 0; rt < 2; ++rt)
#pragma unroll
            for (int ct = 0; ct < 16; ++ct) {
                float sec = sse[cq * 256 + ct * 16 + lr];
#pragma unroll
                for (int j = 0; j < 4; ++j) {
                    float dd = __fsub_rn(__fadd_rn(szv[rt][j], sec), 2.0f * acc[rt][ct][j]);
                    rmin[rt][j] = fminf(rmin[rt][j], dd);
                }
            }
        // reduce over the 16 lanes (bits 0-3) holding this row's 16 cols
#pragma unroll
        for (int m = 1; m < 16; m <<= 1)
#pragma unroll
            for (int rt = 0; rt < 2; ++rt)
#pragma unroll
                for (int j = 0; j < 4; ++j)
                    rmin[rt][j] = fminf(rmin[rt][j], __shfl_xor(rmin[rt][j], m, 64));
        if (lr == 0) {
#pragma unroll
            for (int rt = 0; rt < 2; ++rt)
#pragma unroll
                for (int j = 0; j < 4; ++j)
                    cqmin[(size_t)(wr0 + rt * 16 + lk * 4 + j) * 4 + cq] = rmin[rt][j];
        }
        // emission: all codes with d~ <= rmin + EPS2
#pragma unroll
        for (int rt = 0; rt < 2; ++rt)
#pragma unroll
            for (int j = 0; j < 4; ++j) {
                const float thr = rmin[rt][j] + EPS2;
                const int grow = wr0 + rt * 16 + lk * 4 + j;
#pragma unroll
                for (int ct = 0; ct < 16; ++ct) {
                    float dd = __fsub_rn(__fadd_rn(szv[rt][j], sse[cq * 256 + ct * 16 + lr]),
                                         2.0f * acc[rt][ct][j]);
                    if (dd <= thr) {
                        int s = atomicAdd(&cnt[grow * 4 + cq], 1);
                        if (s < SLOTS) cand[((size_t)grow * 4 + cq) * SLOTS + s] = cq * 256 + ct * 16 + lr;
                    }
                }
            }
    }
}

// ---------------- exact rescore ----------------
// Relevant cqs: cqmin <= gmin + EPS2. Union of their candidates is a superset
// of {c : d~_c <= gmin + EPS2} which contains the exact argmin. Single
// candidate -> done; else exact OpenBLAS-order fmaf dots, lexicographic (d,idx).
__global__ __launch_bounds__(256) void rescore_kernel(
    const float* __restrict__ z, const float* __restrict__ e,
    const float* __restrict__ sz, const float* __restrict__ se,
    const float* __restrict__ cqmin, const int* __restrict__ cnt,
    const int* __restrict__ cand, int* __restrict__ out_idx,
    float* __restrict__ out_idx_f) {
    const int row = blockIdx.x * 256 + threadIdx.x;
    float m0 = cqmin[(size_t)row * 4 + 0];
    float m1 = cqmin[(size_t)row * 4 + 1];
    float m2 = cqmin[(size_t)row * 4 + 2];
    float m3 = cqmin[(size_t)row * 4 + 3];
    const float gmin = fminf(fminf(m0, m1), fminf(m2, m3));
    const float thr = gmin + EPS2;

    int ncand = 0, first_c = 0;
    bool need_scan = false;
#pragma unroll
    for (int cq = 0; cq < 4; ++cq) {
        if (cqmin[(size_t)row * 4 + cq] <= thr) {
            int n = cnt[(size_t)row * 4 + cq];
            if (n > SLOTS) { need_scan = true; }
            else {
                for (int s = 0; s < n; ++s) {
                    int c = cand[((size_t)row * 4 + cq) * SLOTS + s];
                    if (ncand == 0) first_c = c;
                    ++ncand;
                }
            }
        }
    }
    int bi;
    if (!need_scan && ncand == 1) {
        bi = first_c;
    } else {
        const float szr = sz[row];
        const float* zr = z + (size_t)row * ZDIM;
        float bd = __builtin_inff();
        bi = 0;
#pragma unroll 1
        for (int cq = 0; cq < 4; ++cq) {
            if (cqmin[(size_t)row * 4 + cq] > thr) continue;
            int n = cnt[(size_t)row * 4 + cq];
            if (n > SLOTS) {
                for (int c = cq * 256; c < cq * 256 + 256; ++c) {
                    const float* er = e + (size_t)c * ZDIM;
                    float m = 0.0f;
                    for (int k = 0; k < ZDIM; ++k) m = fmaf(zr[k], er[k], m);
                    float d = __fsub_rn(__fadd_rn(szr, se[c]), 2.0f * m);
                    if (d < bd || (d == bd && c < bi)) { bd = d; bi = c; }
                }
            } else {
                for (int s = 0; s < n; ++s) {
                    int c = cand[((size_t)row * 4 + cq) * SLOTS + s];
                    const float* er = e + (size_t)c * ZDIM;
                    float m = 0.0f;
                    for (int k = 0; k < ZDIM; ++k) m = fmaf(zr[k], er[k], m);
                    float d = __fsub_rn(__fadd_rn(szr, se[c]), 2.0f * m);
                    if (d < bd || (d == bd && c < bi)) { bd = d; bi = c; }
                }
            }
        }
    }
    out_idx[row] = bi;
    out_idx_f[row] = (float)bi;
}

// ---------------- z_q_st + loss partial (no atomics) ----------------
__global__ __launch_bounds__(256) void zq_loss_kernel(
    const float* __restrict__ z, const float* __restrict__ e,
    const int* __restrict__ idx, float* __restrict__ out,
    double* __restrict__ partial) {
    const int tid = threadIdx.x;
    const int rl  = tid >> 6;
    const int ln  = tid & 63;
    const int row0 = blockIdx.x * 32;

    float acc = 0.0f;
#pragma unroll
    for (int it = 0; it < 8; ++it) {
        int row = row0 + it * 4 + rl;
        int code = idx[row];
        const float4 vz = *(const float4*)(z + (size_t)row  * ZDIM + ln * 4);
        const float4 vq = *(const float4*)(e + (size_t)code * ZDIM + ln * 4);
        float4 o;
        float dx = __fsub_rn(vq.x, vz.x);
        float dy = __fsub_rn(vq.y, vz.y);
        float dz_ = __fsub_rn(vq.z, vz.z);
        float dw = __fsub_rn(vq.w, vz.w);
        o.x = __fadd_rn(vz.x, dx);
        o.y = __fadd_rn(vz.y, dy);
        o.z = __fadd_rn(vz.z, dz_);
        o.w = __fadd_rn(vz.w, dw);
        *(float4*)(out + (size_t)row * ZDIM + ln * 4) = o;
        acc = __fadd_rn(acc, __fmul_rn(dx, dx));
        acc = __fadd_rn(acc, __fmul_rn(dy, dy));
        acc = __fadd_rn(acc, __fmul_rn(dz_, dz_));
        acc = __fadd_rn(acc, __fmul_rn(dw, dw));
    }

    __shared__ double red[256];
    red[tid] = (double)acc;
    __syncthreads();
#pragma unroll
    for (int s = 128; s > 0; s >>= 1) {
        if (tid < s) red[tid] += red[tid + s];
        __syncthreads();
    }
    if (tid == 0) partial[blockIdx.x] = red[0];
}

__global__ __launch_bounds__(256) void loss_final_kernel(
    const double* __restrict__ partial, float* __restrict__ out_loss) {
    const int tid = threadIdx.x;
    double s = 0.0;
    for (int i = tid; i < ZQ_BLOCKS; i += 256) s += partial[i];
    __shared__ double red[256];
    red[tid] = s;
    __syncthreads();
#pragma unroll
    for (int st = 128; st > 0; st >>= 1) {
        if (tid < st) red[tid] += red[tid + st];
        __syncthreads();
    }
    if (tid == 0) {
        double M = red[0] / 16777216.0;
        float m32 = (float)M;
        out_loss[0] = __fadd_rn(m32, __fmul_rn(0.25f, m32));
    }
}

extern "C" void kernel_launch(void* const* d_in, const int* in_sizes, int n_in,
                              void* d_out, int out_size, void* d_ws, size_t ws_size,
                              hipStream_t stream) {
    const float* z = (const float*)d_in[0];
    const float* e = (const float*)d_in[1];
    float* out = (float*)d_out;
    char* ws = (char*)d_ws;

    size_t off = 0;
    double* partial = (double*)(ws + off); off += ZQ_BLOCKS * sizeof(double);     // 16 KB
    float*  sz      = (float*) (ws + off); off += (size_t)N_ROWS * 4;             // 256 KB
    float*  se      = (float*) (ws + off); off += (size_t)KCODES * 4;             // 4 KB
    int*    idx     = (int*)   (ws + off); off += (size_t)N_ROWS * 4;             // 256 KB
    u16*    ehg     = (u16*)   (ws + off); off += (size_t)KCODES * ZDIM * 2;      // 512 KB
    u16*    elg     = (u16*)   (ws + off); off += (size_t)KCODES * ZDIM * 2;      // 512 KB
    float*  cqmin   = (float*) (ws + off); off += (size_t)N_ROWS * 4 * 4;         // 1 MB
    int*    cnt     = (int*)   (ws + off); off += (size_t)N_ROWS * 4 * 4;         // 1 MB
    int*    cand    = (int*)   (ws + off); off += (size_t)N_ROWS * 4 * SLOTS * 4; // 4 MB

    u32* zsplit = (u32*)out;   // packed (zl<<16|zh) in d_out z_q region (64 MB)

    hipMemsetAsync(cnt, 0, (size_t)N_ROWS * 4 * 4, stream);
    split_z_kernel<<<2048, 256, 0, stream>>>(z, zsplit);
    split_e_kernel<<<256, 256, 0, stream>>>(e, ehg, elg);
    rowsq_kernel<<<N_ROWS / 256, 256, 0, stream>>>(z, sz, N_ROWS);
    rowsq_kernel<<<KCODES / 256, 256, 0, stream>>>(e, se, KCODES);
    mfma_argmin_kernel<<<N_ROWS / 128, 256, 0, stream>>>(zsplit, ehg, elg, sz, se, cqmin, cnt, cand);
    rescore_kernel<<<N_ROWS / 256, 256, 0, stream>>>(z, e, sz, se, cqmin, cnt, cand, idx, out + IDX_OFF);
    zq_loss_kernel<<<ZQ_BLOCKS, 256, 0, stream>>>(z, e, idx, out, partial);
    loss_final_kernel<<<1, 256, 0, stream>>>(partial, out + LOSS_OFF);
}